// Round 15
// baseline (635.639 us; speedup 1.0000x reference)
//
#include <hip/hip_runtime.h>

#define TT 2048
#define BB 256
#define XX 64
#define HH 128
#define YY 32
#define SSTR 20          // 16 data + 4 pad floats per kg-slice
#define HBUF (8 * SSTR)  // 160 floats per h buffer

// 256 threads = 4 waves = 1 wave/SIMD.  J=4 outputs/thread, Kg=8.
// R14 ledger: per-SIMD MAC issue is invariant (192 cyc/step); overhead
// (reduce+tail+misc) scales with waves/SIMD and lockstep waves don't hide
// each other's stalls (R12 16w=806 > R13 8w=730 rocprof).  1 wave/SIMD
// sheds the sibling wave's ~90-inst overhead stack and halves tail
// redundancy.  All-DPP reduce keeps exposed dep-bubbles at 4-8 cyc (R4's
// 1-wave failure was libm tails + serial DS-based shfl, both gone).
// kg on lane bits {0,1,3}; jgl on bits {2,4,5}; j0 = 4*(w*8+jgl).
// Reduce: merge 4 partials on bits {0,1} (quad_perm xor1/xor2, exact),
// then row_ror:8 = xor8 on bit3 (direction-agnostic).  Lane finalizes
// output j0+(lane&3); writers = bit3==0 (32 lanes/wave, conflict-free).
// R3: bias after reduction | R5: direction-proof exchanges only | R6:
// waves_per_eu exact pin | R7: pk half-rate | R13: lgkm-only barrier.

typedef float v2f __attribute__((ext_vector_type(2)));
typedef float v4f __attribute__((ext_vector_type(4)));

#define PKFMA(acc, a, b)                                              \
    asm("v_pk_fma_f32 %0, %1, %2, %0 op_sel:[0,0,0] op_sel_hi:[1,1,1]"\
        : "+v"(acc) : "v"(a), "v"(b))

template<int CTRL>
static __device__ __forceinline__ float dpp_mov(float s) {
    return __int_as_float(__builtin_amdgcn_update_dpp(
        0, __float_as_int(s), CTRL, 0xF, 0xF, true));
}

static __device__ __forceinline__ void pin2(v2f& v) {
    asm volatile("" : "+v"(v));
}

// lgkm-only barrier: LDS writes visible, global loads not drained (R13).
static __device__ __forceinline__ void barrier_lgkm() {
    asm volatile("s_waitcnt lgkmcnt(0)" ::: "memory");
    __builtin_amdgcn_s_barrier();
    asm volatile("" ::: "memory");
}

#define LO2(v) __builtin_shufflevector(v, v, 0, 1)
#define HI2(v) __builtin_shufflevector(v, v, 2, 3)

__global__ __launch_bounds__(256)
__attribute__((amdgpu_waves_per_eu(1, 1)))
void rnn_persist_kernel(const float* __restrict__ x,
                        const float* __restrict__ W_ih,
                        const float* __restrict__ W_hh,
                        const float* __restrict__ b_ih,
                        const float* __restrict__ b_hh,
                        const float* __restrict__ W_out,
                        const float* __restrict__ b_out,
                        float* __restrict__ out)
{
    __shared__ __align__(16) float h_lds[2][HBUF];

    const int tid  = threadIdx.x;
    const int b    = blockIdx.x;
    const int w    = tid >> 6;                                   // 0..3
    const int lane = tid & 63;
    const int kg   = (lane & 3) | ((lane >> 1) & 4);             // bits 0,1,3
    const int jgl  = ((lane >> 2) & 1) | (((lane >> 4) & 3) << 1); // bits 2,4,5
    const int jg   = w * 8 + jgl;                                // 0..31
    const int j0   = jg * 4;                                     // 0..124
    const int b0   = lane & 1;
    const int b1   = (lane >> 1) & 1;
    const int o    = lane & 3;            // output this lane finalizes
    const int jw   = j0 + o;
    const int woff = (jw >> 4) * SSTR + (jw & 15);
    const bool writer = ((lane >> 3) & 1) == 0;   // bit3 == 0: 32 lanes/wave

    const float SC = 2.8853900817779268f;   // 2*log2(e)

    // ---- weights into registers (96 floats, prescaled), pinned ----
    v2f whh2[4][8];   // per jj: 16 floats of W_hh[j0+jj][16kg..+16)
    v2f wih2[4][4];   // per jj: 8 floats of W_ih[j0+jj][8kg..+8)
    #pragma unroll
    for (int jj = 0; jj < 4; ++jj) {
        const v2f* ph = (const v2f*)(W_hh + (j0 + jj) * HH + kg * 16);
        #pragma unroll
        for (int c = 0; c < 8; ++c) whh2[jj][c] = ph[c] * SC;
        const v2f* pi = (const v2f*)(W_ih + (j0 + jj) * XX + kg * 8);
        #pragma unroll
        for (int c = 0; c < 4; ++c) wih2[jj][c] = pi[c] * SC;
    }
    #pragma unroll
    for (int jj = 0; jj < 4; ++jj) {
        #pragma unroll
        for (int c = 0; c < 8; ++c) pin2(whh2[jj][c]);
        #pragma unroll
        for (int c = 0; c < 4; ++c) pin2(wih2[jj][c]);
    }
    const float bsel = (b_ih[jw] + b_hh[jw]) * SC;

    const float* xg = x + (size_t)b * TT * XX + kg * 8;

    if (tid < HBUF) h_lds[0][tid] = 0.f;

    v4f xa0 = ((const v4f*)xg)[0];
    v4f xa1 = ((const v4f*)xg)[1];
    v4f xb0 = ((const v4f*)(xg + XX))[0];
    v4f xb1 = ((const v4f*)(xg + XX))[1];
    __syncthreads();

#define STEP(RP, WP, X0, X1)                                               \
    do {                                                                   \
        const v4f* hp = (const v4f*)&h_lds[RP][kg * SSTR];                 \
        const v4f H0 = hp[0], H1 = hp[1], H2 = hp[2], H3 = hp[3];          \
        const v2f x2[4] = { LO2(X0), HI2(X0), LO2(X1), HI2(X1) };          \
        const v2f h2[8] = { LO2(H0), HI2(H0), LO2(H1), HI2(H1),            \
                            LO2(H2), HI2(H2), LO2(H3), HI2(H3) };          \
        float s[4];                                                        \
        _Pragma("unroll")                                                  \
        for (int jj = 0; jj < 4; ++jj) {                                   \
            v2f a = {0.f, 0.f}, c = {0.f, 0.f};                            \
            PKFMA(a, wih2[jj][0], x2[0]); PKFMA(c, wih2[jj][1], x2[1]);    \
            PKFMA(a, wih2[jj][2], x2[2]); PKFMA(c, wih2[jj][3], x2[3]);    \
            PKFMA(a, whh2[jj][0], h2[0]); PKFMA(c, whh2[jj][1], h2[1]);    \
            PKFMA(a, whh2[jj][2], h2[2]); PKFMA(c, whh2[jj][3], h2[3]);    \
            PKFMA(a, whh2[jj][4], h2[4]); PKFMA(c, whh2[jj][5], h2[5]);    \
            PKFMA(a, whh2[jj][6], h2[6]); PKFMA(c, whh2[jj][7], h2[7]);    \
            a = a + c;                                                     \
            s[jj] = a.x + a.y;                                             \
        }                                                                  \
        /* merge-scatter on bit0 (quad_perm xor1, exact) */                \
        float ul = b0 ? s[1] : s[0];                                       \
        float vl = b0 ? s[0] : s[1];                                       \
        ul += dpp_mov<0xB1>(vl);                                           \
        float uh = b0 ? s[3] : s[2];                                       \
        float vh = b0 ? s[2] : s[3];                                       \
        uh += dpp_mov<0xB1>(vh);                                           \
        /* merge-scatter on bit1 (quad_perm xor2, exact) */                \
        float u  = b1 ? uh : ul;                                           \
        float vv = b1 ? ul : uh;                                           \
        u += dpp_mov<0x4E>(vv);                                            \
        /* bit3: row_ror:8 = xor8 (direction-agnostic) */                  \
        u += dpp_mov<0x128>(u);                                            \
        u += bsel;                    /* bias AFTER reduction (R3) */      \
        const float e  = __builtin_amdgcn_exp2f(u);                        \
        const float hn = fmaf(-2.f, __builtin_amdgcn_rcpf(e + 1.f), 1.f);  \
        if (writer) h_lds[WP][woff] = hn;                                  \
        barrier_lgkm();                                                    \
    } while (0)

    for (int t = 0; t < TT; t += 2) {
        STEP(0, 1, xa0, xa1);
        {   // prefetch x(t+2) -- rides across lgkm-only barriers
            const int tn = (t + 2 < TT) ? t + 2 : TT - 1;
            const v4f* xp = (const v4f*)(xg + (size_t)tn * XX);
            xa0 = xp[0]; xa1 = xp[1];
        }
        STEP(1, 0, xb0, xb1);
        {   // prefetch x(t+3)
            const int tn = (t + 3 < TT) ? t + 3 : TT - 1;
            const v4f* xp = (const v4f*)(xg + (size_t)tn * XX);
            xb0 = xp[0]; xb1 = xp[1];
        }
    }
#undef STEP

    // ---- readout: out[b, :] = h_last @ W_out^T + b_out (h in buffer 0) ----
    if (tid < YY) {
        const float* h  = h_lds[0];
        const float* wr = W_out + tid * HH;
        float r0 = 0.f, r1 = 0.f, r2 = 0.f, r3 = 0.f;
        #pragma unroll
        for (int s8 = 0; s8 < 8; ++s8) {   // 8 slices of 16 floats
            #pragma unroll
            for (int c = 0; c < 4; ++c) {
                const float4 wv = *(const float4*)(wr + s8 * 16 + c * 4);
                const float4 hv = *(const float4*)(h + s8 * SSTR + c * 4);
                r0 = fmaf(wv.x, hv.x, r0); r1 = fmaf(wv.y, hv.y, r1);
                r2 = fmaf(wv.z, hv.z, r2); r3 = fmaf(wv.w, hv.w, r3);
            }
        }
        out[b * YY + tid] = b_out[tid] + ((r0 + r1) + (r2 + r3));
    }
}

extern "C" void kernel_launch(void* const* d_in, const int* in_sizes, int n_in,
                              void* d_out, int out_size, void* d_ws, size_t ws_size,
                              hipStream_t stream) {
    const float* x     = (const float*)d_in[0];
    const float* W_ih  = (const float*)d_in[1];
    const float* W_hh  = (const float*)d_in[2];
    const float* b_ih  = (const float*)d_in[3];
    const float* b_hh  = (const float*)d_in[4];
    const float* W_out = (const float*)d_in[5];
    const float* b_out = (const float*)d_in[6];
    float* out = (float*)d_out;

    rnn_persist_kernel<<<BB, 256, 0, stream>>>(x, W_ih, W_hh, b_ih, b_hh,
                                               W_out, b_out, out);
}

// Round 16
// 588.124 us; speedup vs baseline: 1.0808x; 1.0808x over previous
//
#include <hip/hip_runtime.h>

#define TT 2048
#define BB 256
#define XX 64
#define HH 128
#define YY 32
#define SSTR 20          // 16 data + 4 pad floats per kg-slice
#define HBUF (8 * SSTR)  // 160 floats per h buffer

// R13 champion (588us) + ONE change: 4-deep x prefetch.
// R15 ledger: step ~730 cyc invariant to waves/SIMD (R12 16w=806, R13
// 8w=730, R15 4w=735), DS count (R14 flat), barrier vmcnt drain (R13 flat).
// Remaining corridor item never fixed: x reloaded 1 step before consumption
// (~730 cyc < ~900 cyc HBM first-touch latency) -> ~100-170 cyc vmcnt stall
// at the top of every step.  4 register sets, reload t+4 after step t:
// distance ~2200 cyc >> 900.  x-MACs stay first (fill ds_read window).
// Structure: 512 thr = 8 waves = 2/SIMD. J=2, Kg=8; kg on lane bits {0,1,3}.
// Reduce-scatter: merge J=2 at stage 1 (cndmask pair + xor1), then xor2
// (quad_perm) + xor8 (row_ror:8) -- all direction-proof (R5).
// R3: bias after reduction | R6: waves_per_eu exact pin | R7: pk half-rate.

typedef float v2f __attribute__((ext_vector_type(2)));
typedef float v4f __attribute__((ext_vector_type(4)));

#define PKFMA(acc, a, b)                                              \
    asm("v_pk_fma_f32 %0, %1, %2, %0 op_sel:[0,0,0] op_sel_hi:[1,1,1]"\
        : "+v"(acc) : "v"(a), "v"(b))

template<int CTRL>
static __device__ __forceinline__ float dpp_mov(float s) {
    return __int_as_float(__builtin_amdgcn_update_dpp(
        0, __float_as_int(s), CTRL, 0xF, 0xF, true));
}

static __device__ __forceinline__ void pin2(v2f& v) {
    asm volatile("" : "+v"(v));
}

// lgkm-only barrier: LDS writes visible, global loads NOT drained.
static __device__ __forceinline__ void barrier_lgkm() {
    asm volatile("s_waitcnt lgkmcnt(0)" ::: "memory");
    __builtin_amdgcn_s_barrier();
    asm volatile("" ::: "memory");
}

#define LO2(v) __builtin_shufflevector(v, v, 0, 1)
#define HI2(v) __builtin_shufflevector(v, v, 2, 3)

__global__ __launch_bounds__(512)
__attribute__((amdgpu_waves_per_eu(2, 2)))
void rnn_persist_kernel(const float* __restrict__ x,
                        const float* __restrict__ W_ih,
                        const float* __restrict__ W_hh,
                        const float* __restrict__ b_ih,
                        const float* __restrict__ b_hh,
                        const float* __restrict__ W_out,
                        const float* __restrict__ b_out,
                        float* __restrict__ out)
{
    __shared__ __align__(16) float h_lds[2][HBUF];

    const int tid  = threadIdx.x;
    const int b    = blockIdx.x;
    const int w    = tid >> 6;                                   // 0..7
    const int lane = tid & 63;
    const int kg   = (lane & 3) | ((lane >> 1) & 4);             // bits 0,1,3
    const int jgl  = ((lane >> 2) & 1) | (((lane >> 4) & 3) << 1);
    const int jg   = w * 8 + jgl;                                // 0..63
    const int j0   = jg * 2;
    const int b0   = lane & 1;             // which output this lane finalizes
    const bool writer = (lane & 10) == 0;  // bits 1,3 zero: 16 lanes/wave

    const float SC = 2.8853900817779268f;  // 2*log2(e)

    // ---- weights into registers (48 floats, prescaled), pinned ----
    v2f whh2[2][8];   // per jj: 16 floats of W_hh k-slice
    v2f wih2[2][4];   // per jj: 8 floats of W_ih k-slice
    float bs[2];
    #pragma unroll
    for (int jj = 0; jj < 2; ++jj) {
        const v2f* ph = (const v2f*)(W_hh + (j0 + jj) * HH + kg * 16);
        #pragma unroll
        for (int c = 0; c < 8; ++c) whh2[jj][c] = ph[c] * SC;
        const v2f* pi = (const v2f*)(W_ih + (j0 + jj) * XX + kg * 8);
        #pragma unroll
        for (int c = 0; c < 4; ++c) wih2[jj][c] = pi[c] * SC;
        bs[jj] = (b_ih[j0 + jj] + b_hh[j0 + jj]) * SC;
    }
    #pragma unroll
    for (int jj = 0; jj < 2; ++jj) {
        #pragma unroll
        for (int c = 0; c < 8; ++c) pin2(whh2[jj][c]);
        #pragma unroll
        for (int c = 0; c < 4; ++c) pin2(wih2[jj][c]);
    }
    const float bsel = b0 ? bs[1] : bs[0];

    // writer's output index and LDS slot
    const int jw   = j0 + b0;
    const int woff = (jw >> 4) * SSTR + (jw & 15);

    const float* xg = x + (size_t)b * TT * XX + kg * 8;

    if (tid < HBUF) h_lds[0][tid] = 0.f;

    // ---- 4-deep x prefetch: sets a,b,c,d hold x(t..t+3) ----
    v4f xa0 = ((const v4f*)xg)[0];
    v4f xa1 = ((const v4f*)xg)[1];
    v4f xb0 = ((const v4f*)(xg + XX))[0];
    v4f xb1 = ((const v4f*)(xg + XX))[1];
    v4f xc0 = ((const v4f*)(xg + 2 * XX))[0];
    v4f xc1 = ((const v4f*)(xg + 2 * XX))[1];
    v4f xd0 = ((const v4f*)(xg + 3 * XX))[0];
    v4f xd1 = ((const v4f*)(xg + 3 * XX))[1];
    __syncthreads();

#define STEP(RP, WP, X0, X1)                                              \
    do {                                                                  \
        const v4f* hp = (const v4f*)&h_lds[RP][kg * SSTR];                \
        const v4f H0 = hp[0], H1 = hp[1], H2 = hp[2], H3 = hp[3];         \
        const v2f h2[8] = { LO2(H0), HI2(H0), LO2(H1), HI2(H1),           \
                            LO2(H2), HI2(H2), LO2(H3), HI2(H3) };         \
        const v2f x2[4] = { LO2(X0), HI2(X0), LO2(X1), HI2(X1) };         \
        float s[2];                                                       \
        _Pragma("unroll")                                                 \
        for (int jj = 0; jj < 2; ++jj) {                                  \
            v2f a = {0.f, 0.f}, c = {0.f, 0.f};                           \
            PKFMA(a, wih2[jj][0], x2[0]); PKFMA(c, wih2[jj][1], x2[1]);   \
            PKFMA(a, wih2[jj][2], x2[2]); PKFMA(c, wih2[jj][3], x2[3]);   \
            PKFMA(a, whh2[jj][0], h2[0]); PKFMA(c, whh2[jj][1], h2[1]);   \
            PKFMA(a, whh2[jj][2], h2[2]); PKFMA(c, whh2[jj][3], h2[3]);   \
            PKFMA(a, whh2[jj][4], h2[4]); PKFMA(c, whh2[jj][5], h2[5]);   \
            PKFMA(a, whh2[jj][6], h2[6]); PKFMA(c, whh2[jj][7], h2[7]);   \
            a = a + c;                                                    \
            s[jj] = a.x + a.y;                                            \
        }                                                                 \
        /* reduce-scatter over kg: merge outputs on bit0, then xor2,xor8 */\
        float u = b0 ? s[1] : s[0];   /* kept output's partial */         \
        float v = b0 ? s[0] : s[1];   /* given to xor1 partner */         \
        u += dpp_mov<0xB1>(v);        /* quad_perm [1,0,3,2] = xor1 */    \
        u += dpp_mov<0x4E>(u);        /* quad_perm [2,3,0,1] = xor2 */    \
        u += dpp_mov<0x128>(u);       /* row_ror:8 = xor8 (dir-proof) */  \
        u += bsel;                    /* bias AFTER reduction (R3) */     \
        const float e  = __builtin_amdgcn_exp2f(u);                       \
        const float hn = fmaf(-2.f, __builtin_amdgcn_rcpf(e + 1.f), 1.f); \
        if (writer) h_lds[WP][woff] = hn;                                 \
        barrier_lgkm();               /* lgkm only: x loads ride across */\
    } while (0)

#define RELOAD(XS0, XS1, TN)                                              \
    do {                                                                  \
        const int tn_ = ((TN) < TT) ? (TN) : TT - 1;                      \
        const v4f* xp_ = (const v4f*)(xg + (size_t)tn_ * XX);             \
        XS0 = xp_[0]; XS1 = xp_[1];                                       \
    } while (0)

    for (int t = 0; t < TT; t += 4) {
        STEP(0, 1, xa0, xa1);  RELOAD(xa0, xa1, t + 4);
        STEP(1, 0, xb0, xb1);  RELOAD(xb0, xb1, t + 5);
        STEP(0, 1, xc0, xc1);  RELOAD(xc0, xc1, t + 6);
        STEP(1, 0, xd0, xd1);  RELOAD(xd0, xd1, t + 7);
    }
#undef STEP
#undef RELOAD

    // ---- readout: out[b, :] = h_last @ W_out^T + b_out (h in buffer 0) ----
    if (tid < YY) {
        const float* h  = h_lds[0];
        const float* wr = W_out + tid * HH;
        float r0 = 0.f, r1 = 0.f, r2 = 0.f, r3 = 0.f;
        #pragma unroll
        for (int s8 = 0; s8 < 8; ++s8) {   // 8 slices of 16 floats
            #pragma unroll
            for (int c = 0; c < 4; ++c) {
                const float4 wv = *(const float4*)(wr + s8 * 16 + c * 4);
                const float4 hv = *(const float4*)(h + s8 * SSTR + c * 4);
                r0 = fmaf(wv.x, hv.x, r0); r1 = fmaf(wv.y, hv.y, r1);
                r2 = fmaf(wv.z, hv.z, r2); r3 = fmaf(wv.w, hv.w, r3);
            }
        }
        out[b * YY + tid] = b_out[tid] + ((r0 + r1) + (r2 + r3));
    }
}

extern "C" void kernel_launch(void* const* d_in, const int* in_sizes, int n_in,
                              void* d_out, int out_size, void* d_ws, size_t ws_size,
                              hipStream_t stream) {
    const float* x     = (const float*)d_in[0];
    const float* W_ih  = (const float*)d_in[1];
    const float* W_hh  = (const float*)d_in[2];
    const float* b_ih  = (const float*)d_in[3];
    const float* b_hh  = (const float*)d_in[4];
    const float* W_out = (const float*)d_in[5];
    const float* b_out = (const float*)d_in[6];
    float* out = (float*)d_out;

    rnn_persist_kernel<<<BB, 512, 0, stream>>>(x, W_ih, W_hh, b_ih, b_hh,
                                               W_out, b_out, out);
}